// Round 8
// baseline (303.480 us; speedup 1.0000x reference)
//
#include <hip/hip_runtime.h>
#include <stdint.h>

// x: (32, 256, 58, 58) f32 binary {0,1};  w: (256, 256, 3, 3) f32
// out: (32, 256, 56, 56) f32 = alpha[o]*(2S - 2304), S = XNOR matches
// out = fma(-2*alpha[o], P, 2304*alpha[o]),  P = popcount(xbits ^ wbits)

#define BATCH 32
#define C_IN 256
#define OCH 256
#define HIN 58
#define WIN2 58
#define HOUT 56
#define WOUT 56
#define TAPS 9
#define WWORDS 8            // 256 channels / 32 bits
#define HWIN (HIN * WIN2)   // 3364
#define HWOUT (HOUT * WOUT) // 3136
#define NPOS (BATCH * HWIN) // 107648

typedef unsigned int u32x8 __attribute__((ext_vector_type(8)));

// Fused xor + accumulate-popcount; weight operand pinned to ARCH VGPR class
// ("v"), window word from SGPR (v_xor src0=SGPR legal, 1-SGPR rule ok).
#define XA(accv, xs, wv) { uint32_t _t;                                   \
    asm("v_xor_b32 %0, %2, %3\n\tv_bcnt_u32_b32 %1, %0, %1"               \
        : "=&v"(_t), "+v"(accv) : "s"(xs), "v"(wv)); }

// ---------------------------------------------------------------------------
// Kernel 1: bit-pack x along channels. Thread ↔ (position p, word-pair wp).
// Reads 64B-coalesced per (wp,j) group; writes fully contiguous uint2/wave.
// ---------------------------------------------------------------------------
__global__ __launch_bounds__(256) void pack_x_kernel(
    const float* __restrict__ x, uint32_t* __restrict__ xp)
{
    int t = blockIdx.x * 256 + threadIdx.x;      // 1682 blocks exactly
    int p  = t >> 2;                             // position in [0, NPOS)
    int wp = t & 3;                              // word pair
    int b = p / HWIN;
    int r = p - b * HWIN;
    const float* xb = x + ((size_t)(b * C_IN + wp * 64)) * HWIN + r;
    uint32_t m0 = 0u, m1 = 0u;
    #pragma unroll
    for (int j = 0; j < 32; ++j) {
        float v0 = xb[(size_t)j * HWIN];
        float v1 = xb[(size_t)(j + 32) * HWIN];
        m0 |= (v0 > 0.5f ? 1u : 0u) << j;        // word 2wp,   bit j = ch 64wp+j
        m1 |= (v1 > 0.5f ? 1u : 0u) << j;        // word 2wp+1, bit j = ch 64wp+32+j
    }
    *(uint2*)(xp + (size_t)p * WWORDS + wp * 2) = make_uint2(m0, m1);
}

// ---------------------------------------------------------------------------
// Kernel 2: pack weights O-MINOR: wq[(tap*8 + word)*256 + o] so the main
// kernel's per-lane (lane = o) weight loads are stride-1 coalesced.
// Also per-o scale/bias.
// ---------------------------------------------------------------------------
__global__ __launch_bounds__(256) void pack_w_kernel(
    const float* __restrict__ wt, uint32_t* __restrict__ wq,
    float* __restrict__ sA, float* __restrict__ sB)
{
    int o = blockIdx.x;
    int c = threadIdx.x;
    const float* wb = wt + ((size_t)o * C_IN + c) * TAPS;
    float wv[TAPS];
    float s = 0.f;
    #pragma unroll
    for (int t = 0; t < TAPS; ++t) {
        wv[t] = wb[t];
        s += fabsf(wv[t]);
    }
    int wave = c >> 6, lane = c & 63;
    #pragma unroll
    for (int t = 0; t < TAPS; ++t) {
        unsigned long long m = __ballot(wv[t] >= 0.0f);
        if (lane == 0) {
            // word index w2 = wave*2 holds channels wave*64..+31 (bit j = ch)
            wq[(size_t)(t * 8 + wave * 2)     * OCH + o] = (uint32_t)m;
            wq[(size_t)(t * 8 + wave * 2 + 1) * OCH + o] = (uint32_t)(m >> 32);
        }
    }
    __shared__ float red[256];
    red[c] = s;
    __syncthreads();
    for (int off = 128; off > 0; off >>= 1) {
        if (c < off) red[c] += red[c + off];
        __syncthreads();
    }
    if (c == 0) {
        float alpha = red[0] / (float)(C_IN * HWIN);   // n = C*H*W per reference
        sA[o] = -2.0f * alpha;
        sB[o] = (float)(C_IN * TAPS) * alpha;          // 2304 * alpha
    }
}

// ---------------------------------------------------------------------------
// Kernel 3: main — lane = output channel; FULLY STRAIGHT-LINE hot path.
// R11 post-mortem chain: R3-R7 all showed the allocator AGPR-homes any
// array live across a `#pragma unroll 1` loop boundary (VGPR_Count 28..52,
// always < demand), and the "v" asm constraints then pay one v_accvgpr
// copy per use (R7: 224 VALU/pos model = 109us measured). Fix is
// structural, not a budget knob:
//  - rows OUTER, positions INNER, everything unrolled -> no loop
//    boundaries in the hot path, nothing to AGPR-home (~60 arch VGPRs
//    demand). Worst case even if homed: copies bound to 72/wave (1.8%)
//    because each weight word is reused 14x per residency.
//  - wrow[24] loaded per row (live range = one row body only).
//  - x-window slides: 16 s_load_dwordx8 col-groups per row, wave-uniform,
//    3 live at a time; all in-bounds (cols ox0..ox0+15 <= 57). The old
//    past-the-end prefetch is gone.
//  - two accumulator chains (word-parity split) keep same-dest bcnt
//    dep-stride at 4 instrs; P = accA[i]+accB[i] at the end.
// Store: o-per-lane stores are 64-segment, so stage in LDS [64][57]
// (stride 57 odd -> 2-way max = free) and flush coalesced.
// ---------------------------------------------------------------------------
__global__ __launch_bounds__(256)
__attribute__((amdgpu_waves_per_eu(4, 4)))
void xnor_main_kernel(
    const uint32_t* __restrict__ xp, const uint32_t* __restrict__ wq,
    const float* __restrict__ sA, const float* __restrict__ sB,
    float* __restrict__ out)
{
    __shared__ float olds[64 * 57];              // 14,592 B

    int rj = blockIdx.x;                         // row-job 0..1791
    int b  = rj / HOUT;
    int oy = rj - b * HOUT;
    int obase = blockIdx.y * 64;
    int lane = threadIdx.x & 63;
    int wv_id = __builtin_amdgcn_readfirstlane((int)(threadIdx.x >> 6));
    int o = obase + lane;

    float sAv = sA[o];
    float sBv = sB[o];

    int ox0 = wv_id * 14;                        // this wave's first position

    uint32_t accA[14], accB[14];
    #pragma unroll
    for (int i = 0; i < 14; ++i) { accA[i] = 0u; accB[i] = 0u; }

#define DO_ROW(r)                                                         \
    {                                                                     \
        uint32_t wrow[24];                                                \
        _Pragma("unroll")                                                 \
        for (int k = 0; k < 24; ++k)                                      \
            wrow[k] = wq[(size_t)((r) * 24 + k) * OCH + o];               \
        const uint32_t* rp = xp +                                         \
            (((size_t)b * HIN + oy + (r)) * WIN2 + ox0) * WWORDS;         \
        u32x8 c0 = *(const u32x8*)(rp);                                   \
        u32x8 c1 = *(const u32x8*)(rp + 8);                               \
        _Pragma("unroll")                                                 \
        for (int i = 0; i < 14; ++i) {                                    \
            u32x8 c2 = *(const u32x8*)(rp + (size_t)(i + 2) * 8);         \
            _Pragma("unroll")                                             \
            for (int k = 0; k < 8; ++k)                                   \
                XA(((k & 1) ? accB[i] : accA[i]), c0[k], wrow[k]);        \
            _Pragma("unroll")                                             \
            for (int k = 0; k < 8; ++k)                                   \
                XA(((k & 1) ? accB[i] : accA[i]), c1[k], wrow[8 + k]);    \
            _Pragma("unroll")                                             \
            for (int k = 0; k < 8; ++k)                                   \
                XA(((k & 1) ? accB[i] : accA[i]), c2[k], wrow[16 + k]);   \
            c0 = c1; c1 = c2;                                             \
        }                                                                 \
    }

    DO_ROW(0)
    DO_ROW(1)
    DO_ROW(2)
#undef DO_ROW

    #pragma unroll
    for (int i = 0; i < 14; ++i) {
        float P = (float)(accA[i] + accB[i]);
        olds[lane * 57 + (ox0 + i)] = fmaf(sAv, P, sBv);
    }

    __syncthreads();

    // Coalesced flush: 64 o-rows x 56 positions = 3584 f32 by 256 threads.
    size_t obb = ((size_t)b * OCH + obase) * HWOUT + (size_t)oy * WOUT;
    int tau = threadIdx.x;
    #pragma unroll 1
    for (int i = 0; i < 14; ++i) {
        int flat = i * 256 + tau;                // 0..3583
        int op = flat / 56;
        int pp = flat - op * 56;
        out[obb + (size_t)op * HWOUT + pp] = olds[op * 57 + pp];
    }
}

// ---------------------------------------------------------------------------
extern "C" void kernel_launch(void* const* d_in, const int* in_sizes, int n_in,
                              void* d_out, int out_size, void* d_ws, size_t ws_size,
                              hipStream_t stream)
{
    const float* x  = (const float*)d_in[0];
    const float* wt = (const float*)d_in[1];
    float* out = (float*)d_out;

    char* ws = (char*)d_ws;
    uint32_t* xp = (uint32_t*)ws;                               // 3,444,736 B
    uint32_t* wq = (uint32_t*)(ws + 3444736);                   //    73,728 B
    float*    sA = (float*)(ws + 3444736 + 73728);              //     1,024 B
    float*    sB = (float*)(ws + 3444736 + 73728 + 1024);       //     1,024 B

    // 1) pack x: 430,592 threads / 256 = 1682 blocks exactly
    pack_x_kernel<<<dim3(1682), dim3(256), 0, stream>>>(x, xp);

    // 2) pack weights (o-minor) + scales
    pack_w_kernel<<<dim3(OCH), dim3(256), 0, stream>>>(wt, wq, sA, sB);

    // 3) main: 1792 row-jobs x 4 o-groups of 64
    xnor_main_kernel<<<dim3(1792, 4), dim3(256), 0, stream>>>(xp, wq, sA, sB, out);
}

// Round 9
// 285.284 us; speedup vs baseline: 1.0638x; 1.0638x over previous
//
#include <hip/hip_runtime.h>
#include <stdint.h>

// x: (32, 256, 58, 58) f32 binary {0,1};  w: (256, 256, 3, 3) f32
// out: (32, 256, 56, 56) f32 = alpha[o]*(2S - 2304)
// R12: i8 MFMA implicit conv. A = 2x-1, B = 2bw-1 (both {+1,-1} i8):
//   acc = sum_k A*B = 2S - 2304 exactly; out = alpha[o] * acc.
// VALU path abandoned: R3-R8 showed the allocator AGPR-homes long-lived
// arrays (VGPR_Count 28..52 < demand) and copies cost 1.5x essential; even
// perfect codegen bounds it at ~75us. i8 MFMA ideal = 27us (4404 TOPS).

#define BATCH 32
#define C_IN 256
#define OCH 256
#define HIN 58
#define WIN2 58
#define HOUT 56
#define WOUT 56
#define TAPS 9
#define WWORDS 8            // 256 channels / 32 bits
#define HWIN (HIN * WIN2)   // 3364
#define HWOUT (HOUT * WOUT) // 3136
#define NPOS (BATCH * HWIN) // 107648

#define AP 144              // LDS bytes per input position (128 ch + 16 pad:
                            // stride%128=16 -> ds_read_b128 slots rotate, conflict-free)
#define NAPOS 232           // 4 input rows * 58
#define BCH 8192            // one B K-step chunk: 256 o * 32 k i8

typedef int   i32x4  __attribute__((ext_vector_type(4)));
typedef int   i32x16 __attribute__((ext_vector_type(16)));
typedef float f32x4  __attribute__((ext_vector_type(4)));

// MFMA via inline asm (sidesteps builtin-signature risk; ISA form verbatim).
// "+v" pins acc to arch VGPRs — the class the asm demands, so no AGPR copies.
#define MFMA(acc, va, vb) \
    asm volatile("v_mfma_i32_32x32x32_i8 %0, %1, %2, %0" : "+v"(acc) : "v"(va), "v"(vb))

// ---------------------------------------------------------------------------
// Kernel 1: bit-pack x along channels (UNCHANGED, verified R1-R8).
// xp[pos][word k] bit j = (x channel 32k+j > 0.5), pos = b*3364 + h*58 + w.
// ---------------------------------------------------------------------------
__global__ __launch_bounds__(256) void pack_x_kernel(
    const float* __restrict__ x, uint32_t* __restrict__ xp)
{
    int t = blockIdx.x * 256 + threadIdx.x;      // 1682 blocks exactly
    int p  = t >> 2;
    int wp = t & 3;
    int b = p / HWIN;
    int r = p - b * HWIN;
    const float* xb = x + ((size_t)(b * C_IN + wp * 64)) * HWIN + r;
    uint32_t m0 = 0u, m1 = 0u;
    #pragma unroll
    for (int j = 0; j < 32; ++j) {
        float v0 = xb[(size_t)j * HWIN];
        float v1 = xb[(size_t)(j + 32) * HWIN];
        m0 |= (v0 > 0.5f ? 1u : 0u) << j;
        m1 |= (v1 > 0.5f ? 1u : 0u) << j;
    }
    *(uint2*)(xp + (size_t)p * WWORDS + wp * 2) = make_uint2(m0, m1);
}

// ---------------------------------------------------------------------------
// Kernel 2: pack weights to i8 {+1,-1}: wq8[o][tap*256 + c] = sign(w>=0).
// Also alpha per o: sA[o] = sum|w| / (C*H*W).
// ---------------------------------------------------------------------------
__global__ __launch_bounds__(256) void pack_w8_kernel(
    const float* __restrict__ wt, char* __restrict__ wq8, float* __restrict__ sA)
{
    int o = blockIdx.x;
    int c = threadIdx.x;
    const float* wb = wt + ((size_t)o * C_IN + c) * TAPS;
    float s = 0.f;
    char sg[TAPS];
    #pragma unroll
    for (int t = 0; t < TAPS; ++t) {
        float v = wb[t];
        s += fabsf(v);
        sg[t] = (v >= 0.0f) ? (char)1 : (char)-1;
    }
    #pragma unroll
    for (int t = 0; t < TAPS; ++t)
        wq8[(size_t)o * (TAPS * C_IN) + t * C_IN + c] = sg[t];  // lanes: c consecutive -> coalesced

    __shared__ float red[256];
    red[c] = s;
    __syncthreads();
    for (int off = 128; off > 0; off >>= 1) {
        if (c < off) red[c] += red[c + off];
        __syncthreads();
    }
    if (c == 0) sA[o] = red[0] / (float)(C_IN * HWIN);
}

// ---------------------------------------------------------------------------
// Kernel 3: main i8-MFMA conv. Block = 2 output rows (M=128: 112 valid + 16
// discarded) x N=256 o. 8 waves, wave = 2M x 2N quad of 32x32x32 tiles.
// A (x, +-1): expanded from bit-packed xp into LDS per K-half (4 rows x 58
//   pos x 128 ch, stride AP=144 -> conflict-free frag reads, zero addr VALU:
//   all offsets fold into ds imm).
// B (w, +-1): 8KB K-step chunks, double-buffered, global load prefetched 2
//   steps ahead, ONE barrier per step.
// k-layout risk is void: A and B use the identical channel ordering, and a
// dot product is invariant under any lane/k permutation the HW applies.
// Epilogue: 4 quarter-M phases through LDS (Cbuf [o][36] f32) -> coalesced.
// ---------------------------------------------------------------------------
__global__ __launch_bounds__(512)
__attribute__((amdgpu_waves_per_eu(4, 4)))
void xnor_mfma_kernel(
    const uint32_t* __restrict__ xp, const char* __restrict__ wq8,
    const float* __restrict__ sA, float* __restrict__ out)
{
    __shared__ __attribute__((aligned(16))) char lds[NAPOS * AP + 2 * BCH]; // 49,792 B
    char* Alds = lds;
    char* Blds = lds + NAPOS * AP;
    float* Cbuf = (float*)lds;                   // epilogue alias: 256*36*4 = 36,864 B

    int blk = blockIdx.x;                        // 0..895
    int b   = blk / 28;                          // 28 row-pairs per image
    int rp  = blk - b * 28;
    int oy0 = rp * 2;
    int tid  = threadIdx.x;
    int wv   = tid >> 6;
    int lane = tid & 63;
    int l31  = lane & 31;
    int e    = lane >> 5;
    int mgrp = wv & 1;                           // M-half of this wave
    int ngrp = wv >> 1;                          // o-group (64 o)

    // Per-lane A-frag base for the wave's 2 M-subtiles (row = l31).
    int baseA[2];
    #pragma unroll
    for (int mi = 0; mi < 2; ++mi) {
        int p = (mgrp * 2 + mi) * 32 + l31;      // 0..127
        int r = (p * 586) >> 15;                 // p/56 exact for p<=127
        int c = p - 56 * r;
        baseA[mi] = (r * 58 + c) * AP + e * 16;
    }
    int bofsB = (ngrp * 64 + l31) * 32 + e * 16; // B-frag base (col = l31)
    float al0 = sA[ngrp * 64 + l31];
    float al1 = sA[ngrp * 64 + 32 + l31];

    i32x16 acc00 = {0}, acc01 = {0}, acc10 = {0}, acc11 = {0};
    asm volatile("" : "+v"(acc00), "+v"(acc01), "+v"(acc10), "+v"(acc11)); // pin init above
    asm volatile("s_nop 7\n\ts_nop 7");          // VALU->MFMA srcC hazard guard

// Expand bit-packed x into +-1 bytes for K-half KH (channels KH*128..+127).
// byte = 2*bit-1 via multiply-spread: sp = (nib*0x204081)&0x01010101 puts bit
// j of the nibble at byte j's bit0; byte = ~(sp*0xFE) gives {0x01, 0xFF}.
#define STAGE_A(KH)                                                        \
    {                                                                      \
        _Pragma("unroll")                                                  \
        for (int ir = 0; ir < 4; ++ir) {                                   \
            if (tid < 464) {                                               \
                int iw = tid >> 3, c16 = tid & 7;                          \
                uint32_t wvx = xp[((size_t)(b * HIN + oy0 + ir) * WIN2 + iw) * WWORDS \
                                  + (KH) * 4 + (c16 >> 1)];                \
                uint32_t bits = (c16 & 1) ? (wvx >> 16) : (wvx & 0xFFFFu); \
                i32x4 v;                                                   \
                _Pragma("unroll")                                          \
                for (int d = 0; d < 4; ++d) {                              \
                    uint32_t n  = (bits >> (4 * d)) & 0xFu;                \
                    uint32_t sp = (n * 0x204081u) & 0x01010101u;           \
                    v[d] = (int)~(sp * 0xFEu);                             \
                }                                                          \
                *(i32x4*)(Alds + (ir * 58 + iw) * AP + c16 * 16) = v;      \
            }                                                              \
        }                                                                  \
    }

    STAGE_A(0);

    // B pipeline prologue: chunk 0 staged, chunk 1 in regs.
    const char* wqt = wq8 + (size_t)(tid >> 1) * (TAPS * C_IN) + (tid & 1) * 16;
    char* bw = Blds + ((tid >> 1) * 32 + (tid & 1) * 16);
    i32x4 regP = *(const i32x4*)(wqt + 0);       // s=0: tap0 kh0 kb0
    *(i32x4*)(bw + 0) = regP;                    // buffer 0
    regP = *(const i32x4*)(wqt + 32);            // s=1: tap0 kh0 kb1
    __syncthreads();

    #pragma unroll
    for (int s = 0; s < 72; ++s) {               // s = kh*36 + tap*4 + kb
        if (s == 36) { STAGE_A(1); __syncthreads(); }
        const int kh  = s / 36;
        const int tap = (s - kh * 36) >> 2;
        const int kb  = s & 3;
        const int dy  = tap / 3, dx = tap - dy * 3;
        // prefetch chunk s+2 (clamped; tail redundancy harmless)
        const int s2   = (s + 2 > 71) ? 71 : s + 2;
        const int kh2  = s2 / 36;
        const int tap2 = (s2 - kh2 * 36) >> 2;
        const int kb2  = s2 & 3;
        i32x4 regN = *(const i32x4*)(wqt + tap2 * 256 + kh2 * 128 + kb2 * 32);

        const int ka = (dy * 58 + dx) * AP + kb * 32;      // compile-time imm
        const char* Br = Blds + (s & 1) * BCH;
        i32x4 a0 = *(const i32x4*)(Alds + baseA[0] + ka);
        i32x4 a1 = *(const i32x4*)(Alds + baseA[1] + ka);
        i32x4 b0 = *(const i32x4*)(Br + bofsB);
        i32x4 b1 = *(const i32x4*)(Br + bofsB + 1024);
        MFMA(acc00, a0, b0);
        MFMA(acc01, a0, b1);
        MFMA(acc10, a1, b0);
        MFMA(acc11, a1, b1);

        *(i32x4*)(bw + ((s & 1) ^ 1) * BCH) = regP;        // stage chunk s+1
        regP = regN;
        __syncthreads();
    }

    asm volatile("s_nop 7\n\ts_nop 7");          // MFMA->VALU read guard

    // Epilogue: D layout (verified, dtype-independent): col = l31,
    // row = (reg&3) + 8*(reg>>2) + 4*e. 4 quarter-M phases via Cbuf[o][36].
    size_t ob = ((size_t)b * OCH) * HWOUT + (size_t)oy0 * WOUT;
    #pragma unroll
    for (int q = 0; q < 4; ++q) {
        __syncthreads();
        if (mgrp == (q >> 1)) {
            const int mi = q & 1;
            #pragma unroll
            for (int ni = 0; ni < 2; ++ni) {
                float al = ni ? al1 : al0;
                int o = ngrp * 64 + ni * 32 + l31;
                i32x16 A;
                if (mi == 0 && ni == 0) A = acc00;
                else if (mi == 0)       A = acc01;
                else if (ni == 0)       A = acc10;
                else                    A = acc11;
                #pragma unroll
                for (int g = 0; g < 4; ++g) {
                    f32x4 vv;
                    vv[0] = al * (float)A[4 * g + 0];
                    vv[1] = al * (float)A[4 * g + 1];
                    vv[2] = al * (float)A[4 * g + 2];
                    vv[3] = al * (float)A[4 * g + 3];
                    int pl = g * 8 + 4 * e;                // pos within quarter
                    *(f32x4*)(Cbuf + (size_t)o * 36 + pl) = vv;
                }
            }
        }
        __syncthreads();
        #pragma unroll 1
        for (int i = 0; i < 16; ++i) {           // flush 256 o x 32 pos
            int idx = i * 512 + tid;
            int o = idx >> 5, pl = idx & 31;
            int pg = q * 32 + pl;
            if (pg < 112) {
                int r = (pg >= 56) ? 1 : 0;
                int c = pg - 56 * r;
                out[ob + (size_t)o * HWOUT + r * WOUT + c] = Cbuf[o * 36 + pl];
            }
        }
    }
#undef STAGE_A
}

// ---------------------------------------------------------------------------
extern "C" void kernel_launch(void* const* d_in, const int* in_sizes, int n_in,
                              void* d_out, int out_size, void* d_ws, size_t ws_size,
                              hipStream_t stream)
{
    const float* x  = (const float*)d_in[0];
    const float* wt = (const float*)d_in[1];
    float* out = (float*)d_out;

    char* ws = (char*)d_ws;
    uint32_t* xp  = (uint32_t*)ws;                          // 3,444,736 B
    char*     wq8 = (char*)(ws + 3444736);                  //   589,824 B
    float*    sAp = (float*)(ws + 3444736 + 589824);        //     1,024 B

    // 1) pack x bits: 1682 blocks exactly
    pack_x_kernel<<<dim3(1682), dim3(256), 0, stream>>>(x, xp);

    // 2) pack weights to +-1 i8 + alpha
    pack_w8_kernel<<<dim3(OCH), dim3(256), 0, stream>>>(wt, wq8, sAp);

    // 3) main: 32 images x 28 output-row-pairs
    xnor_mfma_kernel<<<dim3(896), dim3(512), 0, stream>>>(xp, wq8, sAp, out);
}

// Round 10
// 268.874 us; speedup vs baseline: 1.1287x; 1.0610x over previous
//
#include <hip/hip_runtime.h>
#include <stdint.h>

// x: (32, 256, 58, 58) f32 binary {0,1};  w: (256, 256, 3, 3) f32
// out: (32, 256, 56, 56) f32 = alpha[o]*(2S - 2304)
// R13: i8 MFMA implicit conv, B direct-from-global.
// R9 post-mortem: MfmaUtil 28% = exactly the 30.7us MFMA floor inside a
// 100us kernel; idle time = 72 per-step barriers (B LDS staging) + 6.19M
// bank conflicts (B rows stride 32B -> 2-way on every ds_read_b128).
// B is 590KB read by every block -> L2-resident; so B moves to registers
// straight from global (step-major repack, 3-deep prefetch), the K-loop
// keeps only 3 barriers (half-K A restage), and B bank conflicts vanish.

#define BATCH 32
#define C_IN 256
#define OCH 256
#define HIN 58
#define WIN2 58
#define HOUT 56
#define WOUT 56
#define TAPS 9
#define WWORDS 8            // 256 channels / 32 bits
#define HWIN (HIN * WIN2)   // 3364
#define HWOUT (HOUT * WOUT) // 3136
#define NPOS (BATCH * HWIN) // 107648

#define AP 144              // LDS bytes per input position (128 ch + 16 pad:
                            // stride = 9*16, odd multiple of 16 -> ds_read_b128
                            // slots rotate over all 8 -> conflict-free)
#define NAPOS 232           // 4 input rows * 58

typedef int   i32x4  __attribute__((ext_vector_type(4)));
typedef int   i32x16 __attribute__((ext_vector_type(16)));
typedef float f32x4  __attribute__((ext_vector_type(4)));

// MFMA via inline asm (verified R9, absmax 0.0). "+v" pins acc to the class
// the asm demands, so no per-use copies.
#define MFMA(acc, va, vb) \
    asm volatile("v_mfma_i32_32x32x32_i8 %0, %1, %2, %0" : "+v"(acc) : "v"(va), "v"(vb))

// ---------------------------------------------------------------------------
// Kernel 1: bit-pack x along channels (UNCHANGED, verified R1-R9).
// xp[pos][word k] bit j = (x channel 32k+j > 0.5), pos = b*3364 + h*58 + w.
// ---------------------------------------------------------------------------
__global__ __launch_bounds__(256) void pack_x_kernel(
    const float* __restrict__ x, uint32_t* __restrict__ xp)
{
    int t = blockIdx.x * 256 + threadIdx.x;      // 1682 blocks exactly
    int p  = t >> 2;
    int wp = t & 3;
    int b = p / HWIN;
    int r = p - b * HWIN;
    const float* xb = x + ((size_t)(b * C_IN + wp * 64)) * HWIN + r;
    uint32_t m0 = 0u, m1 = 0u;
    #pragma unroll
    for (int j = 0; j < 32; ++j) {
        float v0 = xb[(size_t)j * HWIN];
        float v1 = xb[(size_t)(j + 32) * HWIN];
        m0 |= (v0 > 0.5f ? 1u : 0u) << j;
        m1 |= (v1 > 0.5f ? 1u : 0u) << j;
    }
    *(uint2*)(xp + (size_t)p * WWORDS + wp * 2) = make_uint2(m0, m1);
}

// ---------------------------------------------------------------------------
// Kernel 2: pack weights to i8 {+1,-1}, STEP-MAJOR for the main kernel's
// direct-global B-fragment loads:
//   wq8s[((s*2 + e)*256 + o)*16 + j]  with  s = kh*36 + tap*4 + kb,
//   weight channel c = kh*128 + kb*32 + e*16 + j.
// A 64-lane fragment load (lane o consecutive, e fixed) then covers 4KB
// contiguous -> perfectly coalesced. Also alpha per o.
// ---------------------------------------------------------------------------
__global__ __launch_bounds__(256) void pack_w8_kernel(
    const float* __restrict__ wt, char* __restrict__ wq8s, float* __restrict__ sA)
{
    int o = blockIdx.x;
    int c = threadIdx.x;
    const float* wb = wt + ((size_t)o * C_IN + c) * TAPS;
    float s = 0.f;
    char sg[TAPS];
    #pragma unroll
    for (int t = 0; t < TAPS; ++t) {
        float v = wb[t];
        s += fabsf(v);
        sg[t] = (v >= 0.0f) ? (char)1 : (char)-1;
    }
    int kh = c >> 7;
    int kb = (c >> 5) & 3;
    int e  = (c >> 4) & 1;
    int j  = c & 15;
    #pragma unroll
    for (int t = 0; t < TAPS; ++t) {
        int st = kh * 36 + t * 4 + kb;
        wq8s[(size_t)((st * 2 + e) * 256 + o) * 16 + j] = sg[t];
    }

    __shared__ float red[256];
    red[c] = s;
    __syncthreads();
    for (int off = 128; off > 0; off >>= 1) {
        if (c < off) red[c] += red[c + off];
        __syncthreads();
    }
    if (c == 0) sA[o] = red[0] / (float)(C_IN * HWIN);
}

// ---------------------------------------------------------------------------
// Kernel 3: main i8-MFMA conv. Block = 2 output rows (M=128: 112 valid + 16
// discarded) x N=256 o. 8 waves, wave = 2M x 2N quad of 32x32x32 tiles.
// A (x, +-1): expanded from bit-packed xp into LDS per K-half (4 rows x 58
//   pos x 128 ch, stride AP=144 -> conflict-free frag reads, offsets fold
//   into ds imm). Restaged once at s=36 (3 barriers total in the K-loop).
// B (w, +-1): registers straight from global (L2-resident), 3-deep prefetch.
// k-layout risk void: A and B use the identical channel ordering; a dot
// product is invariant under the HW's lane/k permutation.
// Epilogue: 4 quarter-M phases through LDS (Cbuf [o][36] f32) -> coalesced.
// ---------------------------------------------------------------------------
__global__ __launch_bounds__(512)
void xnor_mfma_kernel(
    const uint32_t* __restrict__ xp, const char* __restrict__ wq8s,
    const float* __restrict__ sA, float* __restrict__ out)
{
    __shared__ __attribute__((aligned(16))) char lds[36864]; // A 33,408 / Cbuf 36,864
    char* Alds = lds;
    float* Cbuf = (float*)lds;                   // epilogue alias

    int blk = blockIdx.x;                        // 0..895
    int b   = blk / 28;                          // 28 row-pairs per image
    int rp  = blk - b * 28;
    int oy0 = rp * 2;
    int tid  = threadIdx.x;
    int wv   = tid >> 6;
    int lane = tid & 63;
    int l31  = lane & 31;
    int e    = lane >> 5;
    int mgrp = wv & 1;                           // M-half of this wave
    int ngrp = wv >> 1;                          // o-group (64 o)

    // Per-lane A-frag base for the wave's 2 M-subtiles (row = l31).
    int baseA[2];
    #pragma unroll
    for (int mi = 0; mi < 2; ++mi) {
        int p = (mgrp * 2 + mi) * 32 + l31;      // 0..127
        int r = (p * 586) >> 15;                 // p/56 exact for p<=127
        int c = p - 56 * r;
        baseA[mi] = (r * 58 + c) * AP + e * 16;
    }
    // B-fragment per-lane base in step-major wq8s; step stride = 8192 B.
    const char* pb = wq8s + ((size_t)e * 256 + (size_t)(ngrp * 64 + l31)) * 16;
    float al0 = sA[ngrp * 64 + l31];
    float al1 = sA[ngrp * 64 + 32 + l31];

    i32x16 acc00 = {0}, acc01 = {0}, acc10 = {0}, acc11 = {0};
    asm volatile("" : "+v"(acc00), "+v"(acc01), "+v"(acc10), "+v"(acc11)); // pin init above
    asm volatile("s_nop 7\n\ts_nop 7");          // VALU->MFMA srcC hazard guard

// Expand bit-packed x into +-1 bytes for K-half KH (channels KH*128..+127).
// byte = 2*bit-1 via multiply-spread (verified R9).
#define STAGE_A(KH)                                                        \
    {                                                                      \
        _Pragma("unroll")                                                  \
        for (int ir = 0; ir < 4; ++ir) {                                   \
            if (tid < 464) {                                               \
                int iw = tid >> 3, c16 = tid & 7;                          \
                uint32_t wvx = xp[((size_t)(b * HIN + oy0 + ir) * WIN2 + iw) * WWORDS \
                                  + (KH) * 4 + (c16 >> 1)];                \
                uint32_t bits = (c16 & 1) ? (wvx >> 16) : (wvx & 0xFFFFu); \
                i32x4 v;                                                   \
                _Pragma("unroll")                                          \
                for (int d = 0; d < 4; ++d) {                              \
                    uint32_t n  = (bits >> (4 * d)) & 0xFu;                \
                    uint32_t sp = (n * 0x204081u) & 0x01010101u;           \
                    v[d] = (int)~(sp * 0xFEu);                             \
                }                                                          \
                *(i32x4*)(Alds + (ir * 58 + iw) * AP + c16 * 16) = v;      \
            }                                                              \
        }                                                                  \
    }

    STAGE_A(0);

    // B prefetch prologue: steps 0,1,2 in registers.
    i32x4 rb0[3], rb1[3];
    #pragma unroll
    for (int q = 0; q < 3; ++q) {
        rb0[q] = *(const i32x4*)(pb + (size_t)q * 8192);
        rb1[q] = *(const i32x4*)(pb + (size_t)q * 8192 + 512);
    }
    __syncthreads();

    #pragma unroll
    for (int s = 0; s < 72; ++s) {               // s = kh*36 + tap*4 + kb
        if (s == 36) {                           // half-K A restage: the ONLY
            __syncthreads();                     // mid-loop barriers
            STAGE_A(1);
            __syncthreads();
        }
        const int kh  = s / 36;
        const int tap = (s - kh * 36) >> 2;
        const int kb  = s & 3;
        const int dy  = tap / 3, dx = tap - dy * 3;
        const int ka  = (dy * 58 + dx) * AP + kb * 32;     // compile-time imm

        i32x4 a0 = *(const i32x4*)(Alds + baseA[0] + ka);
        i32x4 a1 = *(const i32x4*)(Alds + baseA[1] + ka);
        i32x4 b0 = rb0[s % 3];
        i32x4 b1 = rb1[s % 3];
        MFMA(acc00, a0, b0);
        MFMA(acc01, a0, b1);
        MFMA(acc10, a1, b0);
        MFMA(acc11, a1, b1);

        const int s3 = (s + 3 > 71) ? 71 : s + 3;          // tail reload harmless
        rb0[s % 3] = *(const i32x4*)(pb + (size_t)s3 * 8192);
        rb1[s % 3] = *(const i32x4*)(pb + (size_t)s3 * 8192 + 512);
    }

    asm volatile("s_nop 7\n\ts_nop 7");          // MFMA->VALU read guard

    // Epilogue (verbatim R9, verified): D layout col = l31,
    // row = (reg&3) + 8*(reg>>2) + 4*e. 4 quarter-M phases via Cbuf[o][36].
    size_t ob = ((size_t)b * OCH) * HWOUT + (size_t)oy0 * WOUT;
    #pragma unroll
    for (int q = 0; q < 4; ++q) {
        __syncthreads();
        if (mgrp == (q >> 1)) {
            const int mi = q & 1;
            #pragma unroll
            for (int ni = 0; ni < 2; ++ni) {
                float al = ni ? al1 : al0;
                int o = ngrp * 64 + ni * 32 + l31;
                i32x16 A;
                if (mi == 0 && ni == 0) A = acc00;
                else if (mi == 0)       A = acc01;
                else if (ni == 0)       A = acc10;
                else                    A = acc11;
                #pragma unroll
                for (int g = 0; g < 4; ++g) {
                    f32x4 vv;
                    vv[0] = al * (float)A[4 * g + 0];
                    vv[1] = al * (float)A[4 * g + 1];
                    vv[2] = al * (float)A[4 * g + 2];
                    vv[3] = al * (float)A[4 * g + 3];
                    int pl = g * 8 + 4 * e;                // pos within quarter
                    *(f32x4*)(Cbuf + (size_t)o * 36 + pl) = vv;
                }
            }
        }
        __syncthreads();
        #pragma unroll 1
        for (int i = 0; i < 16; ++i) {           // flush 256 o x 32 pos
            int idx = i * 512 + tid;
            int o = idx >> 5, pl = idx & 31;
            int pg = q * 32 + pl;
            if (pg < 112) {
                int r = (pg >= 56) ? 1 : 0;
                int c = pg - 56 * r;
                out[ob + (size_t)o * HWOUT + r * WOUT + c] = Cbuf[o * 36 + pl];
            }
        }
    }
#undef STAGE_A
}

// ---------------------------------------------------------------------------
extern "C" void kernel_launch(void* const* d_in, const int* in_sizes, int n_in,
                              void* d_out, int out_size, void* d_ws, size_t ws_size,
                              hipStream_t stream)
{
    const float* x  = (const float*)d_in[0];
    const float* wt = (const float*)d_in[1];
    float* out = (float*)d_out;

    char* ws = (char*)d_ws;
    uint32_t* xp   = (uint32_t*)ws;                         // 3,444,736 B
    char*     wq8s = (char*)(ws + 3444736);                 //   589,824 B
    float*    sAp  = (float*)(ws + 3444736 + 589824);       //     1,024 B

    // 1) pack x bits: 1682 blocks exactly
    pack_x_kernel<<<dim3(1682), dim3(256), 0, stream>>>(x, xp);

    // 2) pack weights to +-1 i8, step-major + alpha
    pack_w8_kernel<<<dim3(OCH), dim3(256), 0, stream>>>(wt, wq8s, sAp);

    // 3) main: 32 images x 28 output-row-pairs
    xnor_mfma_kernel<<<dim3(896), dim3(512), 0, stream>>>(xp, wq8s, sAp, out);
}